// Round 1
// baseline (439.302 us; speedup 1.0000x reference)
//
#include <hip/hip_runtime.h>
#include <stdint.h>

#define N_NODES 100000
#define N_EDGES 1600000
#define NFEAT 256
#define NHID 64
#define OUT_ELEMS (N_NODES * NHID)

// ---------------------------------------------------------------------------
// Kernel 1: support = x @ W   [100000,256] x [256,64] fp32
// 64 rows per block, K=256 fully staged in LDS, 4x4 register tile per thread.
// ---------------------------------------------------------------------------
__global__ __launch_bounds__(256, 2) void gcn_gemm(const float* __restrict__ x,
                                                   const float* __restrict__ W,
                                                   float* __restrict__ support) {
  __shared__ float xs[64][NFEAT + 4];  // +4 floats pad to break bank aliasing
  const int tid = threadIdx.x;
  const int row0 = blockIdx.x * 64;

  // cooperative load: 64 rows x 256 floats = 4096 float4, 16 per thread
#pragma unroll
  for (int it = 0; it < 16; ++it) {
    int idx = it * 256 + tid;
    int r = idx >> 6;             // 64 float4 per row
    int kc = (idx & 63) << 2;     // float offset within row
    float4 v = make_float4(0.f, 0.f, 0.f, 0.f);
    if (row0 + r < N_NODES)
      v = *reinterpret_cast<const float4*>(&x[(size_t)(row0 + r) * NFEAT + kc]);
    *reinterpret_cast<float4*>(&xs[r][kc]) = v;
  }
  __syncthreads();

  const int c4 = (tid & 15) << 2;  // 4 output cols
  const int r4 = (tid >> 4) << 2;  // 4 output rows (within tile)
  float acc[4][4];
#pragma unroll
  for (int i = 0; i < 4; ++i)
#pragma unroll
    for (int j = 0; j < 4; ++j) acc[i][j] = 0.f;

  for (int kb = 0; kb < NFEAT; kb += 4) {
    float wv[4][4];  // [k][c]
#pragma unroll
    for (int j = 0; j < 4; ++j) {
      float4 t = *reinterpret_cast<const float4*>(&W[(kb + j) * NHID + c4]);
      wv[j][0] = t.x; wv[j][1] = t.y; wv[j][2] = t.z; wv[j][3] = t.w;
    }
    float xv[4][4];  // [r][k]
#pragma unroll
    for (int i = 0; i < 4; ++i) {
      float4 t = *reinterpret_cast<const float4*>(&xs[r4 + i][kb]);
      xv[i][0] = t.x; xv[i][1] = t.y; xv[i][2] = t.z; xv[i][3] = t.w;
    }
#pragma unroll
    for (int i = 0; i < 4; ++i)
#pragma unroll
      for (int c = 0; c < 4; ++c)
#pragma unroll
        for (int j = 0; j < 4; ++j)
          acc[i][c] = fmaf(xv[i][j], wv[j][c], acc[i][c]);
  }

#pragma unroll
  for (int i = 0; i < 4; ++i) {
    int r = row0 + r4 + i;
    if (r < N_NODES) {
      float4 o = make_float4(acc[i][0], acc[i][1], acc[i][2], acc[i][3]);
      *reinterpret_cast<float4*>(&support[(size_t)r * NHID + c4]) = o;
    }
  }
}

// ---------------------------------------------------------------------------
// Kernel 2: scatter-add  agg[dst] += support[src] * w   (64 lanes = 64 feats)
// ---------------------------------------------------------------------------
__global__ __launch_bounds__(256) void gcn_scatter(const float* __restrict__ support,
                                                   const int* __restrict__ esrc,
                                                   const int* __restrict__ edst,
                                                   const float* __restrict__ ew,
                                                   float* __restrict__ agg) {
  const int lane = threadIdx.x & 63;
  const int sub = threadIdx.x >> 6;  // 0..3 (wave id in block)
  for (int e = blockIdx.x * 4 + sub; e < N_EDGES; e += gridDim.x * 4) {
    int s = esrc[e];
    int d = edst[e];
    float w = ew[e];
    float v = support[(size_t)s * NHID + lane] * w;
    atomicAdd(&agg[(size_t)d * NHID + lane], v);
  }
}

// ---------------------------------------------------------------------------
// Kernel 3: in-place finalize on d_out: relu(v + b), dropout (JAX threefry),
// keep-scale x2.  Partitionable threefry: elem i -> threefry2x32((0,42),(0,i)),
// bits = b0 ^ b1, keep iff top bit clear (uniform < 0.5).
// ---------------------------------------------------------------------------
__device__ __forceinline__ unsigned rotl32(unsigned x, int r) {
  return (x << r) | (x >> (32 - r));
}

__global__ __launch_bounds__(256) void gcn_finalize(float* __restrict__ io,
                                                    const float* __restrict__ b) {
  unsigned i = blockIdx.x * 256u + threadIdx.x;
  if (i >= (unsigned)OUT_ELEMS) return;
  float v = io[i] + b[i & 63];
  float h = fmaxf(v, 0.f) * 2.0f;  // relu then / keep (keep = 0.5)

  const unsigned ks0 = 0u;
  const unsigned ks1 = 42u;
  const unsigned ks2 = 0x1BD11BDAu ^ ks0 ^ ks1;
  unsigned x0 = 0u + ks0;  // hi32(count) = 0
  unsigned x1 = i + ks1;   // lo32(count) = i

#define TF_R4(a, bb, c, d)                       \
  x0 += x1; x1 = rotl32(x1, a);  x1 ^= x0;       \
  x0 += x1; x1 = rotl32(x1, bb); x1 ^= x0;       \
  x0 += x1; x1 = rotl32(x1, c);  x1 ^= x0;       \
  x0 += x1; x1 = rotl32(x1, d);  x1 ^= x0;

  TF_R4(13, 15, 26, 6);  x0 += ks1; x1 += ks2 + 1u;
  TF_R4(17, 29, 16, 24); x0 += ks2; x1 += ks0 + 2u;
  TF_R4(13, 15, 26, 6);  x0 += ks0; x1 += ks1 + 3u;
  TF_R4(17, 29, 16, 24); x0 += ks1; x1 += ks2 + 4u;
  TF_R4(13, 15, 26, 6);  x0 += ks2; x1 += ks0 + 5u;
#undef TF_R4

  unsigned bits = x0 ^ x1;
  io[i] = (bits & 0x80000000u) ? 0.f : h;
}

// ---------------------------------------------------------------------------
extern "C" void kernel_launch(void* const* d_in, const int* in_sizes, int n_in,
                              void* d_out, int out_size, void* d_ws, size_t ws_size,
                              hipStream_t stream) {
  const float* x = (const float*)d_in[0];
  const float* W = (const float*)d_in[1];
  const float* b = (const float*)d_in[2];
  const int* esrc = (const int*)d_in[3];
  const int* edst = (const int*)d_in[4];
  const float* ew = (const float*)d_in[5];
  float* out = (float*)d_out;
  float* support = (float*)d_ws;  // 25.6 MB scratch

  // agg accumulates into d_out via atomics -> must be zeroed every call
  hipMemsetAsync(d_out, 0, (size_t)OUT_ELEMS * sizeof(float), stream);

  gcn_gemm<<<(N_NODES + 63) / 64, 256, 0, stream>>>(x, W, support);
  gcn_scatter<<<25600, 256, 0, stream>>>(support, esrc, edst, ew, out);
  gcn_finalize<<<(OUT_ELEMS + 255) / 256, 256, 0, stream>>>(out, b);
}

// Round 2
// 368.877 us; speedup vs baseline: 1.1909x; 1.1909x over previous
//
#include <hip/hip_runtime.h>
#include <stdint.h>

#define N_NODES 100000
#define N_EDGES 1600000
#define NFEAT 256
#define NHID 64
#define OUT_ELEMS (N_NODES * NHID)
#define SCAN_B 512
#define NB1 ((N_NODES + SCAN_B - 1) / SCAN_B)  // 196

// ---------------------------------------------------------------------------
// Kernel 1: support = x @ W   [100000,256] x [256,64] fp32
// ---------------------------------------------------------------------------
__global__ __launch_bounds__(256, 2) void gcn_gemm(const float* __restrict__ x,
                                                   const float* __restrict__ W,
                                                   float* __restrict__ support) {
  __shared__ float xs[64][NFEAT + 4];
  const int tid = threadIdx.x;
  const int row0 = blockIdx.x * 64;

#pragma unroll
  for (int it = 0; it < 16; ++it) {
    int idx = it * 256 + tid;
    int r = idx >> 6;
    int kc = (idx & 63) << 2;
    float4 v = make_float4(0.f, 0.f, 0.f, 0.f);
    if (row0 + r < N_NODES)
      v = *reinterpret_cast<const float4*>(&x[(size_t)(row0 + r) * NFEAT + kc]);
    *reinterpret_cast<float4*>(&xs[r][kc]) = v;
  }
  __syncthreads();

  const int c4 = (tid & 15) << 2;
  const int r4 = (tid >> 4) << 2;
  float acc[4][4];
#pragma unroll
  for (int i = 0; i < 4; ++i)
#pragma unroll
    for (int j = 0; j < 4; ++j) acc[i][j] = 0.f;

  for (int kb = 0; kb < NFEAT; kb += 4) {
    float wv[4][4];
#pragma unroll
    for (int j = 0; j < 4; ++j) {
      float4 t = *reinterpret_cast<const float4*>(&W[(kb + j) * NHID + c4]);
      wv[j][0] = t.x; wv[j][1] = t.y; wv[j][2] = t.z; wv[j][3] = t.w;
    }
    float xv[4][4];
#pragma unroll
    for (int i = 0; i < 4; ++i) {
      float4 t = *reinterpret_cast<const float4*>(&xs[r4 + i][kb]);
      xv[i][0] = t.x; xv[i][1] = t.y; xv[i][2] = t.z; xv[i][3] = t.w;
    }
#pragma unroll
    for (int i = 0; i < 4; ++i)
#pragma unroll
      for (int c = 0; c < 4; ++c)
#pragma unroll
        for (int j = 0; j < 4; ++j)
          acc[i][c] = fmaf(xv[i][j], wv[j][c], acc[i][c]);
  }

#pragma unroll
  for (int i = 0; i < 4; ++i) {
    int r = row0 + r4 + i;
    if (r < N_NODES) {
      float4 o = make_float4(acc[i][0], acc[i][1], acc[i][2], acc[i][3]);
      *reinterpret_cast<float4*>(&support[(size_t)r * NHID + c4]) = o;
    }
  }
}

// ---------------------------------------------------------------------------
// CSR build: histogram -> exclusive scan (3 kernels) -> cursor fill
// ---------------------------------------------------------------------------
__global__ __launch_bounds__(256) void gcn_hist(const int* __restrict__ edst,
                                                int* __restrict__ deg) {
  int e = blockIdx.x * 256 + threadIdx.x;
  if (e < N_EDGES) atomicAdd(&deg[edst[e]], 1);
}

__global__ __launch_bounds__(SCAN_B) void gcn_scanA(const int* __restrict__ deg,
                                                    int* __restrict__ blocksum) {
  __shared__ int sh[SCAN_B];
  int t = threadIdx.x, g = blockIdx.x * SCAN_B + t;
  sh[t] = (g < N_NODES) ? deg[g] : 0;
  __syncthreads();
  for (int s = SCAN_B / 2; s > 0; s >>= 1) {
    if (t < s) sh[t] += sh[t + s];
    __syncthreads();
  }
  if (t == 0) blocksum[blockIdx.x] = sh[0];
}

__global__ void gcn_scanB(int* __restrict__ blocksum) {
  if (threadIdx.x == 0 && blockIdx.x == 0) {
    int acc = 0;
    for (int i = 0; i < NB1; ++i) {
      int v = blocksum[i];
      blocksum[i] = acc;
      acc += v;
    }
  }
}

__global__ __launch_bounds__(SCAN_B) void gcn_scanC(const int* __restrict__ deg,
                                                    const int* __restrict__ blocksum,
                                                    int* __restrict__ offs,
                                                    int* __restrict__ pos) {
  __shared__ int sh[SCAN_B];
  int t = threadIdx.x, g = blockIdx.x * SCAN_B + t;
  int v = (g < N_NODES) ? deg[g] : 0;
  sh[t] = v;
  __syncthreads();
  for (int s = 1; s < SCAN_B; s <<= 1) {
    int a = (t >= s) ? sh[t - s] : 0;
    __syncthreads();
    sh[t] += a;
    __syncthreads();
  }
  int excl = sh[t] - v + blocksum[blockIdx.x];
  if (g < N_NODES) {
    offs[g] = excl;
    pos[g] = excl;
  }
}

__global__ __launch_bounds__(256) void gcn_fill(const int* __restrict__ esrc,
                                                const int* __restrict__ edst,
                                                const float* __restrict__ ew,
                                                int* __restrict__ pos,
                                                int* __restrict__ csr_src,
                                                float* __restrict__ csr_w) {
  int e = blockIdx.x * 256 + threadIdx.x;
  if (e < N_EDGES) {
    int d = edst[e];
    int slot = atomicAdd(&pos[d], 1);
    csr_src[slot] = esrc[e];
    csr_w[slot] = ew[e];
  }
}

// ---------------------------------------------------------------------------
// Pull + finalize: one wave per dst node, lane = feature.
// acc = sum_j support[src_j][lane] * w_j ; out = dropout(relu(acc + b)) * 2
// ---------------------------------------------------------------------------
__device__ __forceinline__ unsigned rotl32(unsigned x, int r) {
  return (x << r) | (x >> (32 - r));
}

__device__ __forceinline__ unsigned threefry_bits(unsigned i) {
  const unsigned ks0 = 0u, ks1 = 42u;
  const unsigned ks2 = 0x1BD11BDAu ^ ks0 ^ ks1;
  unsigned x0 = ks0;       // hi32(count) = 0
  unsigned x1 = i + ks1;   // lo32(count) = i
#define TF_R4(a, bb, c, d)                       \
  x0 += x1; x1 = rotl32(x1, a);  x1 ^= x0;       \
  x0 += x1; x1 = rotl32(x1, bb); x1 ^= x0;       \
  x0 += x1; x1 = rotl32(x1, c);  x1 ^= x0;       \
  x0 += x1; x1 = rotl32(x1, d);  x1 ^= x0;
  TF_R4(13, 15, 26, 6);  x0 += ks1; x1 += ks2 + 1u;
  TF_R4(17, 29, 16, 24); x0 += ks2; x1 += ks0 + 2u;
  TF_R4(13, 15, 26, 6);  x0 += ks0; x1 += ks1 + 3u;
  TF_R4(17, 29, 16, 24); x0 += ks1; x1 += ks2 + 4u;
  TF_R4(13, 15, 26, 6);  x0 += ks2; x1 += ks0 + 5u;
#undef TF_R4
  return x0 ^ x1;
}

__global__ __launch_bounds__(256) void gcn_pull(const float* __restrict__ support,
                                                const int* __restrict__ offs,
                                                const int* __restrict__ deg,
                                                const int* __restrict__ csr_src,
                                                const float* __restrict__ csr_w,
                                                const float* __restrict__ b,
                                                float* __restrict__ out) {
  const int lane = threadIdx.x & 63;
  const int wv = threadIdx.x >> 6;
  const int d = blockIdx.x * 4 + wv;
  if (d >= N_NODES) return;

  const int off = offs[d];
  const int n = deg[d];
  float acc = 0.f;
  int j = off;
  const int end = off + n;
  for (; j + 1 < end; j += 2) {
    int s0 = csr_src[j], s1 = csr_src[j + 1];
    float w0 = csr_w[j], w1 = csr_w[j + 1];
    float v0 = support[(size_t)s0 * NHID + lane];
    float v1 = support[(size_t)s1 * NHID + lane];
    acc = fmaf(v0, w0, acc);
    acc = fmaf(v1, w1, acc);
  }
  if (j < end) {
    int s0 = csr_src[j];
    acc = fmaf(support[(size_t)s0 * NHID + lane], csr_w[j], acc);
  }

  float h = fmaxf(acc + b[lane], 0.f) * 2.0f;
  unsigned i = (unsigned)d * 64u + (unsigned)lane;
  unsigned bits = threefry_bits(i);
  out[i] = (bits & 0x80000000u) ? 0.f : h;
}

// ---------------------------------------------------------------------------
extern "C" void kernel_launch(void* const* d_in, const int* in_sizes, int n_in,
                              void* d_out, int out_size, void* d_ws, size_t ws_size,
                              hipStream_t stream) {
  const float* x = (const float*)d_in[0];
  const float* W = (const float*)d_in[1];
  const float* b = (const float*)d_in[2];
  const int* esrc = (const int*)d_in[3];
  const int* edst = (const int*)d_in[4];
  const float* ew = (const float*)d_in[5];
  float* out = (float*)d_out;

  char* ws = (char*)d_ws;
  float* support = (float*)ws;                          // 25,600,000 B
  int* deg       = (int*)(ws + 25600000);               //    400,000 B
  int* offs      = (int*)(ws + 26000000);               //    400,000 B
  int* pos       = (int*)(ws + 26400000);               //    400,000 B
  int* blocksum  = (int*)(ws + 26800000);               //      4,096 B
  int* csr_src   = (int*)(ws + 26804096);               //  6,400,000 B
  float* csr_w   = (float*)(ws + 33204096);             //  6,400,000 B  (end ~39.6 MB)

  hipMemsetAsync(deg, 0, N_NODES * sizeof(int), stream);

  gcn_gemm<<<(N_NODES + 63) / 64, 256, 0, stream>>>(x, W, support);
  gcn_hist<<<(N_EDGES + 255) / 256, 256, 0, stream>>>(edst, deg);
  gcn_scanA<<<NB1, SCAN_B, 0, stream>>>(deg, blocksum);
  gcn_scanB<<<1, 64, 0, stream>>>(blocksum);
  gcn_scanC<<<NB1, SCAN_B, 0, stream>>>(deg, blocksum, offs, pos);
  gcn_fill<<<(N_EDGES + 255) / 256, 256, 0, stream>>>(esrc, edst, ew, pos, csr_src, csr_w);
  gcn_pull<<<(N_NODES + 3) / 4, 256, 0, stream>>>(support, offs, deg, csr_src, csr_w, b, out);
}

// Round 3
// 334.522 us; speedup vs baseline: 1.3132x; 1.1027x over previous
//
#include <hip/hip_runtime.h>
#include <stdint.h>

#define N_NODES 100000
#define N_EDGES 1600000
#define NFEAT 256
#define NHID 64
#define OUT_ELEMS (N_NODES * NHID)
#define SCAN_B 512
#define NB1 ((N_NODES + SCAN_B - 1) / SCAN_B)  // 196

// ---------------------------------------------------------------------------
// fp32 -> bf16 (round to nearest even)
// ---------------------------------------------------------------------------
__device__ __forceinline__ unsigned short f2bf(float f) {
  unsigned u = __float_as_uint(f);
  u = (u + 0x7FFFu + ((u >> 16) & 1u)) >> 16;
  return (unsigned short)u;
}

// ---------------------------------------------------------------------------
// Kernel 1: support = x @ W  [100000,256] x [256,64], fp32 math, bf16 output
// ---------------------------------------------------------------------------
__global__ __launch_bounds__(256, 2) void gcn_gemm(const float* __restrict__ x,
                                                   const float* __restrict__ W,
                                                   unsigned short* __restrict__ support) {
  __shared__ float xs[64][NFEAT + 4];
  const int tid = threadIdx.x;
  const int row0 = blockIdx.x * 64;

#pragma unroll
  for (int it = 0; it < 16; ++it) {
    int idx = it * 256 + tid;
    int r = idx >> 6;
    int kc = (idx & 63) << 2;
    float4 v = make_float4(0.f, 0.f, 0.f, 0.f);
    if (row0 + r < N_NODES)
      v = *reinterpret_cast<const float4*>(&x[(size_t)(row0 + r) * NFEAT + kc]);
    *reinterpret_cast<float4*>(&xs[r][kc]) = v;
  }
  __syncthreads();

  const int c4 = (tid & 15) << 2;
  const int r4 = (tid >> 4) << 2;
  float acc[4][4];
#pragma unroll
  for (int i = 0; i < 4; ++i)
#pragma unroll
    for (int j = 0; j < 4; ++j) acc[i][j] = 0.f;

  for (int kb = 0; kb < NFEAT; kb += 4) {
    float wv[4][4];
#pragma unroll
    for (int j = 0; j < 4; ++j) {
      float4 t = *reinterpret_cast<const float4*>(&W[(kb + j) * NHID + c4]);
      wv[j][0] = t.x; wv[j][1] = t.y; wv[j][2] = t.z; wv[j][3] = t.w;
    }
    float xv[4][4];
#pragma unroll
    for (int i = 0; i < 4; ++i) {
      float4 t = *reinterpret_cast<const float4*>(&xs[r4 + i][kb]);
      xv[i][0] = t.x; xv[i][1] = t.y; xv[i][2] = t.z; xv[i][3] = t.w;
    }
#pragma unroll
    for (int i = 0; i < 4; ++i)
#pragma unroll
      for (int c = 0; c < 4; ++c)
#pragma unroll
        for (int j = 0; j < 4; ++j)
          acc[i][c] = fmaf(xv[i][j], wv[j][c], acc[i][c]);
  }

#pragma unroll
  for (int i = 0; i < 4; ++i) {
    int r = row0 + r4 + i;
    if (r < N_NODES) {
      ushort4 o;
      o.x = f2bf(acc[i][0]); o.y = f2bf(acc[i][1]);
      o.z = f2bf(acc[i][2]); o.w = f2bf(acc[i][3]);
      *reinterpret_cast<ushort4*>(&support[(size_t)r * NHID + c4]) = o;
    }
  }
}

// ---------------------------------------------------------------------------
// CSR build: histogram -> exclusive scan -> cursor fill (interleaved int2)
// ---------------------------------------------------------------------------
__global__ __launch_bounds__(256) void gcn_hist(const int* __restrict__ edst,
                                                int* __restrict__ deg) {
  int e = blockIdx.x * 256 + threadIdx.x;
  if (e < N_EDGES) atomicAdd(&deg[edst[e]], 1);
}

__global__ __launch_bounds__(SCAN_B) void gcn_scanA(const int* __restrict__ deg,
                                                    int* __restrict__ blocksum) {
  __shared__ int sh[SCAN_B];
  int t = threadIdx.x, g = blockIdx.x * SCAN_B + t;
  sh[t] = (g < N_NODES) ? deg[g] : 0;
  __syncthreads();
  for (int s = SCAN_B / 2; s > 0; s >>= 1) {
    if (t < s) sh[t] += sh[t + s];
    __syncthreads();
  }
  if (t == 0) blocksum[blockIdx.x] = sh[0];
}

// single-block parallel exclusive scan of NB1 (<=256) block sums
__global__ __launch_bounds__(256) void gcn_scanB(int* __restrict__ blocksum) {
  __shared__ int sh[256];
  int t = threadIdx.x;
  int v = (t < NB1) ? blocksum[t] : 0;
  sh[t] = v;
  __syncthreads();
  for (int s = 1; s < 256; s <<= 1) {
    int a = (t >= s) ? sh[t - s] : 0;
    __syncthreads();
    sh[t] += a;
    __syncthreads();
  }
  if (t < NB1) blocksum[t] = sh[t] - v;  // exclusive
}

__global__ __launch_bounds__(SCAN_B) void gcn_scanC(const int* __restrict__ deg,
                                                    const int* __restrict__ blocksum,
                                                    int* __restrict__ offs,
                                                    int* __restrict__ pos) {
  __shared__ int sh[SCAN_B];
  int t = threadIdx.x, g = blockIdx.x * SCAN_B + t;
  int v = (g < N_NODES) ? deg[g] : 0;
  sh[t] = v;
  __syncthreads();
  for (int s = 1; s < SCAN_B; s <<= 1) {
    int a = (t >= s) ? sh[t - s] : 0;
    __syncthreads();
    sh[t] += a;
    __syncthreads();
  }
  int excl = sh[t] - v + blocksum[blockIdx.x];
  if (g < N_NODES) {
    offs[g] = excl;
    pos[g] = excl;
  }
}

__global__ __launch_bounds__(256) void gcn_fill(const int* __restrict__ esrc,
                                                const int* __restrict__ edst,
                                                const float* __restrict__ ew,
                                                int* __restrict__ pos,
                                                int2* __restrict__ csr) {
  int e = blockIdx.x * 256 + threadIdx.x;
  if (e < N_EDGES) {
    int d = edst[e];
    int slot = atomicAdd(&pos[d], 1);
    csr[slot] = make_int2(esrc[e], __float_as_int(ew[e]));
  }
}

// ---------------------------------------------------------------------------
// Pull + finalize: half-wave (32 lanes) per dst node; lane = 2 features
// (bf16 pair). acc = sum_j support[src_j][f..f+1] * w_j ;
// out = dropout(relu(acc + b)) * 2
// ---------------------------------------------------------------------------
__device__ __forceinline__ unsigned rotl32(unsigned x, int r) {
  return (x << r) | (x >> (32 - r));
}

__device__ __forceinline__ unsigned threefry_bits(unsigned i) {
  const unsigned ks0 = 0u, ks1 = 42u;
  const unsigned ks2 = 0x1BD11BDAu ^ ks0 ^ ks1;
  unsigned x0 = ks0;       // hi32(count) = 0
  unsigned x1 = i + ks1;   // lo32(count) = i
#define TF_R4(a, bb, c, d)                       \
  x0 += x1; x1 = rotl32(x1, a);  x1 ^= x0;       \
  x0 += x1; x1 = rotl32(x1, bb); x1 ^= x0;       \
  x0 += x1; x1 = rotl32(x1, c);  x1 ^= x0;       \
  x0 += x1; x1 = rotl32(x1, d);  x1 ^= x0;
  TF_R4(13, 15, 26, 6);  x0 += ks1; x1 += ks2 + 1u;
  TF_R4(17, 29, 16, 24); x0 += ks2; x1 += ks0 + 2u;
  TF_R4(13, 15, 26, 6);  x0 += ks0; x1 += ks1 + 3u;
  TF_R4(17, 29, 16, 24); x0 += ks1; x1 += ks2 + 4u;
  TF_R4(13, 15, 26, 6);  x0 += ks2; x1 += ks0 + 5u;
#undef TF_R4
  return x0 ^ x1;
}

__global__ __launch_bounds__(256) void gcn_pull(const unsigned* __restrict__ support2,
                                                const int* __restrict__ offs,
                                                const int* __restrict__ deg,
                                                const int2* __restrict__ csr,
                                                const float* __restrict__ b,
                                                float* __restrict__ out) {
  const int half = threadIdx.x >> 5;          // which half-wave / node slot (0..7)
  const int l = threadIdx.x & 31;             // lane within half-wave
  const int d = blockIdx.x * 8 + half;
  if (d >= N_NODES) return;

  const int off = offs[d];
  const int n = deg[d];
  float acc0 = 0.f, acc1 = 0.f;

  int j = off;
  const int end = off + n;
  for (; j + 1 < end; j += 2) {
    int2 r0 = csr[j];
    int2 r1 = csr[j + 1];
    unsigned p0 = support2[(size_t)r0.x * 32 + l];
    unsigned p1 = support2[(size_t)r1.x * 32 + l];
    float w0 = __int_as_float(r0.y);
    float w1 = __int_as_float(r1.y);
    acc0 = fmaf(__uint_as_float(p0 << 16), w0, acc0);
    acc1 = fmaf(__uint_as_float(p0 & 0xFFFF0000u), w0, acc1);
    acc0 = fmaf(__uint_as_float(p1 << 16), w1, acc0);
    acc1 = fmaf(__uint_as_float(p1 & 0xFFFF0000u), w1, acc1);
  }
  if (j < end) {
    int2 r0 = csr[j];
    unsigned p0 = support2[(size_t)r0.x * 32 + l];
    float w0 = __int_as_float(r0.y);
    acc0 = fmaf(__uint_as_float(p0 << 16), w0, acc0);
    acc1 = fmaf(__uint_as_float(p0 & 0xFFFF0000u), w0, acc1);
  }

  const int f = l * 2;
  float2 bb = *reinterpret_cast<const float2*>(&b[f]);
  float h0 = fmaxf(acc0 + bb.x, 0.f) * 2.0f;
  float h1 = fmaxf(acc1 + bb.y, 0.f) * 2.0f;
  unsigned i0 = (unsigned)d * 64u + (unsigned)f;
  unsigned m0 = threefry_bits(i0);
  unsigned m1 = threefry_bits(i0 + 1u);
  float2 o;
  o.x = (m0 & 0x80000000u) ? 0.f : h0;
  o.y = (m1 & 0x80000000u) ? 0.f : h1;
  *reinterpret_cast<float2*>(&out[i0]) = o;
}

// ---------------------------------------------------------------------------
extern "C" void kernel_launch(void* const* d_in, const int* in_sizes, int n_in,
                              void* d_out, int out_size, void* d_ws, size_t ws_size,
                              hipStream_t stream) {
  const float* x = (const float*)d_in[0];
  const float* W = (const float*)d_in[1];
  const float* b = (const float*)d_in[2];
  const int* esrc = (const int*)d_in[3];
  const int* edst = (const int*)d_in[4];
  const float* ew = (const float*)d_in[5];
  float* out = (float*)d_out;

  char* ws = (char*)d_ws;
  unsigned short* support = (unsigned short*)ws;        // 12,800,000 B (bf16)
  int* deg       = (int*)(ws + 12800000);               //    400,000 B
  int* offs      = (int*)(ws + 13200000);               //    400,000 B
  int* pos       = (int*)(ws + 13600000);               //    400,000 B
  int* blocksum  = (int*)(ws + 14000000);               //      1,024 B
  int2* csr      = (int2*)(ws + 14001024);              // 12,800,000 B (end ~26.8 MB)

  hipMemsetAsync(deg, 0, N_NODES * sizeof(int), stream);

  gcn_gemm<<<(N_NODES + 63) / 64, 256, 0, stream>>>(x, W, support);
  gcn_hist<<<(N_EDGES + 255) / 256, 256, 0, stream>>>(edst, deg);
  gcn_scanA<<<NB1, SCAN_B, 0, stream>>>(deg, blocksum);
  gcn_scanB<<<1, 256, 0, stream>>>(blocksum);
  gcn_scanC<<<NB1, SCAN_B, 0, stream>>>(deg, blocksum, offs, pos);
  gcn_fill<<<(N_EDGES + 255) / 256, 256, 0, stream>>>(esrc, edst, ew, pos, csr);
  gcn_pull<<<(N_NODES + 7) / 8, 256, 0, stream>>>((const unsigned*)support, offs, deg,
                                                  csr, b, out);
}